// Round 1
// baseline (4470.868 us; speedup 1.0000x reference)
//
#include <hip/hip_runtime.h>

typedef short s16x8 __attribute__((ext_vector_type(8)));
typedef float f32x4 __attribute__((ext_vector_type(4)));

#define LDW 136   // padded LDS row stride in shorts (128 + 8): 4-way max write conflict, 16B-aligned b128 reads

__device__ __forceinline__ unsigned short f2bf(float x) {
    unsigned int u = __builtin_bit_cast(unsigned int, x);
    u = (u + 0x7fffu + ((u >> 16) & 1u)) >> 16;   // RNE
    return (unsigned short)u;
}
__device__ __forceinline__ float bf2f(unsigned int lo) {
    return __builtin_bit_cast(float, lo << 16);
}

__global__ __launch_bounds__(256) void deg_kernel(const int* __restrict__ src,
                                                  const int* __restrict__ dst,
                                                  float* __restrict__ degO,
                                                  float* __restrict__ degI,
                                                  int RE, int E, int N) {
    int idx = blockIdx.x * 256 + threadIdx.x;
    if (idx >= RE) return;
    int r = idx / E;
    atomicAdd(&degO[(size_t)r * N + src[idx]], 1.0f);
    atomicAdd(&degI[(size_t)r * N + dst[idx]], 1.0f);
}

__global__ __launch_bounds__(256) void norm_kernel(float* __restrict__ v, int n) {
    int idx = blockIdx.x * 256 + threadIdx.x;
    if (idx < n) v[idx] = rsqrtf(fmaxf(v[idx], 1.0f));
}

// T[n][c] = bf16( norm[n] * sum_k X[n][k] * W[k][c] )
// X fp32 [nrows][128], W fp32 [128][128] row-major, T bf16 [nrows][128]
__global__ __launch_bounds__(256) void gemm_scale(const float* __restrict__ X,
                                                  const float* __restrict__ W,
                                                  const float* __restrict__ norm,
                                                  unsigned short* __restrict__ T,
                                                  int nrows) {
    __shared__ unsigned short Wl[128 * LDW];  // Wl[n][k] = W[k][n]  (B-operand, transposed)
    __shared__ unsigned short Xl[64 * LDW];   // Xl[r][k]            (A-operand)
    int tid = threadIdx.x;
    int row0 = blockIdx.x * 64;

    // stage W (coalesced global read, transposed LDS write)
    for (int i = tid; i < 128 * 128; i += 256) {
        int k = i >> 7, n = i & 127;
        Wl[n * LDW + k] = f2bf(W[i]);
    }
    // stage X tile as bf16 (coalesced float4 reads)
    const float4* Xv = (const float4*)X;
#pragma unroll
    for (int j = 0; j < 8; ++j) {
        int f4 = tid + j * 256;           // 0..2047 over 64 rows * 32 float4
        int row = f4 >> 5;
        int k0 = (f4 & 31) * 4;
        int gr = row0 + row;
        float4 v = make_float4(0.f, 0.f, 0.f, 0.f);
        if (gr < nrows) v = Xv[(size_t)gr * 32 + (f4 & 31)];
        unsigned long long pk = (unsigned long long)f2bf(v.x)
                              | ((unsigned long long)f2bf(v.y) << 16)
                              | ((unsigned long long)f2bf(v.z) << 32)
                              | ((unsigned long long)f2bf(v.w) << 48);
        *(unsigned long long*)(&Xl[row * LDW + k0]) = pk;
    }
    __syncthreads();

    int wave = tid >> 6, lane = tid & 63;
    int laneM = lane & 15, quad = lane >> 4;
    int m0 = wave * 16;                   // wave's 16 rows within the 64-row tile
    f32x4 acc[8];
#pragma unroll
    for (int ct = 0; ct < 8; ++ct) acc[ct] = (f32x4){0.f, 0.f, 0.f, 0.f};

#pragma unroll
    for (int ks = 0; ks < 4; ++ks) {
        int k = ks * 32 + quad * 8;
        // A frag: A[m=lane&15][k=quad*8+j]
        s16x8 a = *(const s16x8*)(Xl + (m0 + laneM) * LDW + k);
#pragma unroll
        for (int ct = 0; ct < 8; ++ct) {
            // B frag: B[k=quad*8+j][n=lane&15]  via transposed Wl
            s16x8 b = *(const s16x8*)(Wl + (ct * 16 + laneM) * LDW + k);
            acc[ct] = __builtin_amdgcn_mfma_f32_16x16x32_bf16(a, b, acc[ct], 0, 0, 0);
        }
    }

    // C/D: D[row=quad*4+i][col=lane&15]
#pragma unroll
    for (int i = 0; i < 4; ++i) {
        int gr = row0 + m0 + quad * 4 + i;
        if (gr < nrows) {
            float sc = norm[gr];
#pragma unroll
            for (int ct = 0; ct < 8; ++ct) {
                T[(size_t)gr * 128 + ct * 16 + laneM] = f2bf(acc[ct][i] * sc);
            }
        }
    }
}

// one wave per edge: out[dst] += T[src] * normI[dst]
__global__ __launch_bounds__(256) void scatter_add(const unsigned short* __restrict__ T,
                                                   const int* __restrict__ src,
                                                   const int* __restrict__ dst,
                                                   const float* __restrict__ normI,
                                                   float* __restrict__ out,
                                                   int E) {
    int gw = blockIdx.x * 4 + (threadIdx.x >> 6);
    if (gw >= E) return;
    int lane = threadIdx.x & 63;
    int s = src[gw], d = dst[gw];
    float nd = normI[d];
    unsigned int v = ((const unsigned int*)(T + (size_t)s * 128))[lane];  // 2 bf16
    float f0 = bf2f(v & 0xffffu) * nd;
    float f1 = bf2f(v >> 16) * nd;
    float* o = out + (size_t)d * 128 + lane * 2;
    atomicAdd(o, f0);
    atomicAdd(o + 1, f1);
}

__global__ __launch_bounds__(256) void relu_bias(float4* __restrict__ h,
                                                 const float* __restrict__ b,
                                                 int n4) {
    int idx = blockIdx.x * 256 + threadIdx.x;
    if (idx >= n4) return;
    int c4 = idx & 31;
    const float4* bv = (const float4*)b;
    float4 b0 = bv[c4], bA = bv[32 + c4], bB = bv[64 + c4];
    float4 v = h[idx];
    v.x = fmaxf(v.x + b0.x + bA.x + bB.x, 0.f);
    v.y = fmaxf(v.y + b0.y + bA.y + bB.y, 0.f);
    v.z = fmaxf(v.z + b0.z + bA.z + bB.z, 0.f);
    v.w = fmaxf(v.w + b0.w + bA.w + bB.w, 0.f);
    h[idx] = v;
}

__global__ __launch_bounds__(256) void add_bias(float4* __restrict__ h,
                                                const float* __restrict__ b,
                                                int n4) {
    int idx = blockIdx.x * 256 + threadIdx.x;
    if (idx >= n4) return;
    int c4 = idx & 31;
    const float4* bv = (const float4*)b;
    float4 b0 = bv[c4], bA = bv[32 + c4], bB = bv[64 + c4];
    float4 v = h[idx];
    v.x += b0.x + bA.x + bB.x;
    v.y += b0.y + bA.y + bB.y;
    v.z += b0.z + bA.z + bB.z;
    v.w += b0.w + bA.w + bB.w;
    h[idx] = v;
}

extern "C" void kernel_launch(void* const* d_in, const int* in_sizes, int n_in,
                              void* d_out, int out_size, void* d_ws, size_t ws_size,
                              hipStream_t stream) {
    const float* x  = (const float*)d_in[0];
    const int* src  = (const int*)d_in[1];
    const int* dst  = (const int*)d_in[2];
    const float* W1 = (const float*)d_in[3];
    const float* b1 = (const float*)d_in[4];
    const float* W2 = (const float*)d_in[5];
    const float* b2 = (const float*)d_in[6];
    float* out = (float*)d_out;

    const int R = 3;
    int N = in_sizes[0] / 128;
    int E = in_sizes[1] / R;

    size_t h1b = (size_t)N * 128 * 4;      // fp32 accumulator
    size_t nb  = (size_t)R * N * 4;        // one norm array
    size_t Tb  = (size_t)N * 128 * 2;      // bf16 message matrix
    if (ws_size < h1b + 2 * nb + Tb) return;  // fail visibly rather than corrupt

    char* w = (char*)d_ws;
    float* h1            = (float*)w;
    float* normO         = (float*)(w + h1b);
    float* normI         = (float*)(w + h1b + nb);
    unsigned short* T    = (unsigned short*)(w + h1b + 2 * nb);

    // zero h1 + degree accumulators, zero output accumulator
    hipMemsetAsync(h1, 0, h1b + 2 * nb, stream);
    hipMemsetAsync(out, 0, (size_t)N * 128 * 4, stream);

    deg_kernel<<<(R * E + 255) / 256, 256, 0, stream>>>(src, dst, normO, normI, R * E, E, N);
    norm_kernel<<<(2 * R * N + 255) / 256, 256, 0, stream>>>(normO, 2 * R * N);

    int gb = (N + 63) / 64;
    int sb = (E + 3) / 4;

    for (int r = 0; r < R; ++r) {
        gemm_scale<<<gb, 256, 0, stream>>>(x, W1 + (size_t)r * 128 * 128, normO + (size_t)r * N, T, N);
        scatter_add<<<sb, 256, 0, stream>>>(T, src + (size_t)r * E, dst + (size_t)r * E,
                                            normI + (size_t)r * N, h1, E);
    }
    relu_bias<<<(N * 32 + 255) / 256, 256, 0, stream>>>((float4*)h1, b1, N * 32);

    for (int r = 0; r < R; ++r) {
        gemm_scale<<<gb, 256, 0, stream>>>(h1, W2 + (size_t)r * 128 * 128, normO + (size_t)r * N, T, N);
        scatter_add<<<sb, 256, 0, stream>>>(T, src + (size_t)r * E, dst + (size_t)r * E,
                                            normI + (size_t)r * N, out, E);
    }
    add_bias<<<(N * 32 + 255) / 256, 256, 0, stream>>>((float4*)out, b2, N * 32);
}

// Round 2
// 1097.539 us; speedup vs baseline: 4.0735x; 4.0735x over previous
//
#include <hip/hip_runtime.h>

typedef short s16x8 __attribute__((ext_vector_type(8)));
typedef float f32x4 __attribute__((ext_vector_type(4)));

#define LDW 136   // padded LDS row stride in shorts (128 + 8)

__device__ __forceinline__ unsigned short f2bf(float x) {
    unsigned int u = __builtin_bit_cast(unsigned int, x);
    u = (u + 0x7fffu + ((u >> 16) & 1u)) >> 16;   // RNE
    return (unsigned short)u;
}
__device__ __forceinline__ float bf2f(unsigned int lo) {
    return __builtin_bit_cast(float, lo << 16);
}

// ---- topology: degree counts (int atomics, L2-resident 1.2 MB arrays) ----
__global__ __launch_bounds__(256) void deg_kernel(const int* __restrict__ src,
                                                  const int* __restrict__ dst,
                                                  unsigned int* __restrict__ cntO,
                                                  unsigned int* __restrict__ cntI,
                                                  int RE, int E, int N) {
    int idx = blockIdx.x * 256 + threadIdx.x;
    if (idx >= RE) return;
    int r = idx / E;
    atomicAdd(&cntO[(size_t)r * N + src[idx]], 1u);
    atomicAdd(&cntI[(size_t)r * N + dst[idx]], 1u);
}

__global__ __launch_bounds__(256) void norm_kernel(const unsigned int* __restrict__ cntO,
                                                   const unsigned int* __restrict__ cntI,
                                                   float* __restrict__ normO,
                                                   float* __restrict__ normI,
                                                   int RN) {
    int idx = blockIdx.x * 256 + threadIdx.x;
    if (idx < RN)       normO[idx]      = rsqrtf(fmaxf((float)cntO[idx], 1.0f));
    else if (idx < 2*RN) normI[idx - RN] = rsqrtf(fmaxf((float)cntI[idx - RN], 1.0f));
}

// exclusive scan of cntI per relation -> offs, cursor.  grid = R blocks x 1024.
__global__ __launch_bounds__(1024) void scan_kernel(const unsigned int* __restrict__ cnt,
                                                    int* __restrict__ offs,
                                                    int* __restrict__ cursor,
                                                    int N) {
    __shared__ int ws[16];
    int r = blockIdx.x, t = threadIdx.x;
    int lane = t & 63, w = t >> 6;
    const unsigned int* c = cnt + (size_t)r * N;
    int* o  = offs   + (size_t)r * N;
    int* cu = cursor + (size_t)r * N;
    int carry = 0;
    for (int base = 0; base < N; base += 1024) {
        int i = base + t;
        int v = (i < N) ? (int)c[i] : 0;
        int x = v;
#pragma unroll
        for (int d = 1; d < 64; d <<= 1) {
            int y = __shfl_up(x, d, 64);
            if (lane >= d) x += y;
        }
        if (lane == 63) ws[w] = x;
        __syncthreads();
        if (t < 64) {
            int wsum = (t < 16) ? ws[t] : 0;
#pragma unroll
            for (int d = 1; d < 16; d <<= 1) {
                int y = __shfl_up(wsum, d, 16);
                if ((t & 15) >= d) wsum += y;
            }
            if (t < 16) ws[t] = wsum;
        }
        __syncthreads();
        int bofs = carry + (w ? ws[w - 1] : 0);
        if (i < N) { int e = bofs + x - v; o[i] = e; cu[i] = e; }
        int tot = ws[15];
        __syncthreads();
        carry += tot;
    }
}

// counting-sort edges by dst: bucket[r][pos] = src
__global__ __launch_bounds__(256) void bucket_kernel(const int* __restrict__ src,
                                                     const int* __restrict__ dst,
                                                     int* __restrict__ cursor,
                                                     int* __restrict__ bucket,
                                                     int RE, int E, int N) {
    int idx = blockIdx.x * 256 + threadIdx.x;
    if (idx >= RE) return;
    int r = idx / E;
    int d = dst[idx];
    int pos = atomicAdd(&cursor[(size_t)r * N + d], 1);
    bucket[(size_t)r * E + pos] = src[idx];
}

// ---- T[n][c] = bf16( norm[n] * sum_k X[n][k] * W[k][c] ) ----
template <bool BF16IN>
__global__ __launch_bounds__(256) void gemm_scale(const void* __restrict__ Xp,
                                                  const float* __restrict__ W,
                                                  const float* __restrict__ norm,
                                                  unsigned short* __restrict__ T,
                                                  int nrows) {
    __shared__ unsigned short Wl[128 * LDW];  // Wl[n][k] = W[k][n]
    __shared__ unsigned short Xl[64 * LDW];
    int tid = threadIdx.x;
    int row0 = blockIdx.x * 64;

    for (int i = tid; i < 128 * 128; i += 256) {
        int k = i >> 7, n = i & 127;
        Wl[n * LDW + k] = f2bf(W[i]);
    }
#pragma unroll
    for (int j = 0; j < 8; ++j) {
        int f4 = tid + j * 256;           // 64 rows * 32 chunks of 4 elems
        int row = f4 >> 5;
        int k0 = (f4 & 31) * 4;
        int gr = row0 + row;
        if (BF16IN) {
            uint2 v = make_uint2(0u, 0u);
            if (gr < nrows) v = ((const uint2*)Xp)[(size_t)gr * 32 + (f4 & 31)];
            *(uint2*)(&Xl[row * LDW + k0]) = v;
        } else {
            float4 v = make_float4(0.f, 0.f, 0.f, 0.f);
            if (gr < nrows) v = ((const float4*)Xp)[(size_t)gr * 32 + (f4 & 31)];
            unsigned long long pk = (unsigned long long)f2bf(v.x)
                                  | ((unsigned long long)f2bf(v.y) << 16)
                                  | ((unsigned long long)f2bf(v.z) << 32)
                                  | ((unsigned long long)f2bf(v.w) << 48);
            *(unsigned long long*)(&Xl[row * LDW + k0]) = pk;
        }
    }
    __syncthreads();

    int wave = tid >> 6, lane = tid & 63;
    int laneM = lane & 15, quad = lane >> 4;
    int m0 = wave * 16;
    f32x4 acc[8];
#pragma unroll
    for (int ct = 0; ct < 8; ++ct) acc[ct] = (f32x4){0.f, 0.f, 0.f, 0.f};

#pragma unroll
    for (int ks = 0; ks < 4; ++ks) {
        int k = ks * 32 + quad * 8;
        s16x8 a = *(const s16x8*)(Xl + (m0 + laneM) * LDW + k);
#pragma unroll
        for (int ct = 0; ct < 8; ++ct) {
            s16x8 b = *(const s16x8*)(Wl + (ct * 16 + laneM) * LDW + k);
            acc[ct] = __builtin_amdgcn_mfma_f32_16x16x32_bf16(a, b, acc[ct], 0, 0, 0);
        }
    }

#pragma unroll
    for (int i = 0; i < 4; ++i) {
        int gr = row0 + m0 + quad * 4 + i;
        if (gr < nrows) {
            float sc = norm[gr];
#pragma unroll
            for (int ct = 0; ct < 8; ++ct) {
                T[(size_t)gr * 128 + ct * 16 + laneM] = f2bf(acc[ct][i] * sc);
            }
        }
    }
}

// ---- gather: one wave per dst node, fused over R relations + bias (+relu) ----
template <bool RELU, bool BF16OUT>
__global__ __launch_bounds__(256) void gather_kernel(const unsigned short* __restrict__ T, // [R][N][128]
                                                     const int* __restrict__ bucket,       // [R][E]
                                                     const int* __restrict__ offs,         // [R][N]
                                                     const unsigned int* __restrict__ cnt, // [R][N]
                                                     const float* __restrict__ normI,      // [R][N]
                                                     const float* __restrict__ bias,       // [R][128]
                                                     void* __restrict__ out,
                                                     int N, int E) {
    int n = blockIdx.x * 4 + (threadIdx.x >> 6);
    if (n >= N) return;
    int lane = threadIdx.x & 63;
    float a0 = 0.f, a1 = 0.f;
    const float2* bv = (const float2*)bias;
#pragma unroll
    for (int r = 0; r < 3; ++r) {
        float p0 = 0.f, p1 = 0.f;
        int start = offs[(size_t)r * N + n];
        int c = (int)cnt[(size_t)r * N + n];
        const unsigned int* Tr = (const unsigned int*)(T + (size_t)r * N * 128);
        const int* bk = bucket + (size_t)r * E + start;
        for (int base = 0; base < c; base += 64) {
            int m = min(64, c - base);
            int id = (lane < m) ? bk[base + lane] : 0;
            for (int j = 0; j < m; ++j) {
                int s2 = __shfl(id, j, 64);
                unsigned int v = Tr[(size_t)s2 * 64 + lane];
                p0 += bf2f(v & 0xffffu);
                p1 += bf2f(v >> 16);
            }
        }
        float nd = normI[(size_t)r * N + n];
        float2 bb = bv[r * 64 + lane];
        a0 += p0 * nd + bb.x;
        a1 += p1 * nd + bb.y;
    }
    if (RELU) { a0 = fmaxf(a0, 0.f); a1 = fmaxf(a1, 0.f); }
    if (BF16OUT) {
        unsigned int pk = (unsigned int)f2bf(a0) | ((unsigned int)f2bf(a1) << 16);
        ((unsigned int*)out)[(size_t)n * 64 + lane] = pk;
    } else {
        ((float2*)((float*)out + (size_t)n * 128))[lane] = make_float2(a0, a1);
    }
}

extern "C" void kernel_launch(void* const* d_in, const int* in_sizes, int n_in,
                              void* d_out, int out_size, void* d_ws, size_t ws_size,
                              hipStream_t stream) {
    const float* x  = (const float*)d_in[0];
    const int* src  = (const int*)d_in[1];
    const int* dst  = (const int*)d_in[2];
    const float* W1 = (const float*)d_in[3];
    const float* b1 = (const float*)d_in[4];
    const float* W2 = (const float*)d_in[5];
    const float* b2 = (const float*)d_in[6];
    float* out = (float*)d_out;

    const int R = 3;
    int N = in_sizes[0] / 128;
    int E = in_sizes[1] / R;
    int RN = R * N, RE = R * E;

    size_t h1b = (size_t)N * 128 * 2;          // bf16 hidden
    size_t Tb  = (size_t)R * N * 128 * 2;      // bf16 messages, all relations
    size_t ib  = (size_t)RN * 4;               // one int/float [R][N] array
    size_t bb  = (size_t)RE * 4;               // bucketed src ids
    if (ws_size < h1b + Tb + 6 * ib + bb) return;

    char* w = (char*)d_ws;
    unsigned short* h1   = (unsigned short*)w;            w += h1b;
    unsigned short* T    = (unsigned short*)w;            w += Tb;
    unsigned int* cntO   = (unsigned int*)w;              w += ib;
    unsigned int* cntI   = (unsigned int*)w;              w += ib;
    float* normO         = (float*)w;                     w += ib;
    float* normI         = (float*)w;                     w += ib;
    int* offs            = (int*)w;                       w += ib;
    int* cursor          = (int*)w;                       w += ib;
    int* bucket          = (int*)w;

    hipMemsetAsync(cntO, 0, 2 * ib, stream);   // cntO + cntI contiguous

    deg_kernel<<<(RE + 255) / 256, 256, 0, stream>>>(src, dst, cntO, cntI, RE, E, N);
    norm_kernel<<<(2 * RN + 255) / 256, 256, 0, stream>>>(cntO, cntI, normO, normI, RN);
    scan_kernel<<<R, 1024, 0, stream>>>(cntI, offs, cursor, N);
    bucket_kernel<<<(RE + 255) / 256, 256, 0, stream>>>(src, dst, cursor, bucket, RE, E, N);

    int gb = (N + 63) / 64;
    int ngb = (N + 3) / 4;

    // layer 1
    for (int r = 0; r < R; ++r)
        gemm_scale<false><<<gb, 256, 0, stream>>>(x, W1 + (size_t)r * 128 * 128,
                                                  normO + (size_t)r * N,
                                                  T + (size_t)r * N * 128, N);
    gather_kernel<true, true><<<ngb, 256, 0, stream>>>(T, bucket, offs, cntI, normI, b1, h1, N, E);

    // layer 2
    for (int r = 0; r < R; ++r)
        gemm_scale<true><<<gb, 256, 0, stream>>>(h1, W2 + (size_t)r * 128 * 128,
                                                 normO + (size_t)r * N,
                                                 T + (size_t)r * N * 128, N);
    gather_kernel<false, false><<<ngb, 256, 0, stream>>>(T, bucket, offs, cntI, normI, b2, out, N, E);
}

// Round 4
// 929.558 us; speedup vs baseline: 4.8097x; 1.1807x over previous
//
#include <hip/hip_runtime.h>

typedef short s16x8 __attribute__((ext_vector_type(8)));
typedef float f32x4 __attribute__((ext_vector_type(4)));

#define LDW 136   // padded LDS row stride in shorts (128 + 8)
#define CH 4096   // scan chunk size

__device__ __forceinline__ unsigned short f2bf(float x) {
    unsigned int u = __builtin_bit_cast(unsigned int, x);
    u = (u + 0x7fffu + ((u >> 16) & 1u)) >> 16;   // RNE
    return (unsigned short)u;
}
__device__ __forceinline__ float bf2f(unsigned int lo) {
    return __builtin_bit_cast(float, lo << 16);
}

// ---- degree histograms ----
__global__ __launch_bounds__(256) void deg_kernel(const int* __restrict__ src,
                                                  const int* __restrict__ dst,
                                                  unsigned int* __restrict__ cntO,
                                                  unsigned int* __restrict__ cntI,
                                                  int RE, int E, int N) {
    int idx = blockIdx.x * 256 + threadIdx.x;
    if (idx >= RE) return;
    int r = idx / E;
    atomicAdd(&cntO[(size_t)r * N + src[idx]], 1u);
    atomicAdd(&cntI[(size_t)r * N + dst[idx]], 1u);
}

__global__ __launch_bounds__(256) void norm_kernel(const unsigned int* __restrict__ cntO,
                                                   const unsigned int* __restrict__ cntI,
                                                   float* __restrict__ normO,
                                                   float* __restrict__ normI,
                                                   int RN) {
    int idx = blockIdx.x * 256 + threadIdx.x;
    if (idx < RN)        normO[idx]      = rsqrtf(fmaxf((float)cntO[idx], 1.0f));
    else if (idx < 2*RN) normI[idx - RN] = rsqrtf(fmaxf((float)cntI[idx - RN], 1.0f));
}

// ---- W fp32 -> bf16, transposed: WbfT[which][n][k] = bf16(W[which][k][n]) ----
__global__ __launch_bounds__(256) void wconv_kernel(const float* __restrict__ W1,
                                                    const float* __restrict__ W2,
                                                    unsigned short* __restrict__ WbfT,
                                                    int total) {
    int idx = blockIdx.x * 256 + threadIdx.x;
    if (idx >= total) return;
    int which = idx >> 14;
    int k = (idx >> 7) & 127;
    int n = idx & 127;
    int outi = (idx & ~16383) | (n << 7) | k;
    const float* W = (which < 3) ? (W1 + (size_t)which * 16384)
                                 : (W2 + (size_t)(which - 3) * 16384);
    WbfT[outi] = f2bf(W[k * 128 + n]);
}

// ---- two-level scan of cntI per relation ----
__global__ __launch_bounds__(256) void scanA(const unsigned int* __restrict__ cnt,
                                             int* __restrict__ csum, int N, int NC) {
    int r = blockIdx.x / NC, c = blockIdx.x % NC;
    const unsigned int* p = cnt + (size_t)r * N + c * CH;
    int lim = N - c * CH; if (lim > CH) lim = CH;
    int t = threadIdx.x;
    int s = 0;
    for (int i = t; i < lim; i += 256) s += (int)p[i];
#pragma unroll
    for (int d = 32; d; d >>= 1) s += __shfl_down(s, d, 64);
    __shared__ int ws[4];
    if ((t & 63) == 0) ws[t >> 6] = s;
    __syncthreads();
    if (t == 0) csum[blockIdx.x] = ws[0] + ws[1] + ws[2] + ws[3];
}

__global__ __launch_bounds__(256) void scanB(int* __restrict__ csum, int RC, int NC) {
    __shared__ int s[1024];
    int t = threadIdx.x;
    for (int i = t; i < RC; i += 256) s[i] = csum[i];
    __syncthreads();
    if (t < RC / NC) {
        int base = 0;
        for (int c = 0; c < NC; ++c) {
            int v = s[t * NC + c];
            s[t * NC + c] = base;
            base += v;
        }
    }
    __syncthreads();
    for (int i = t; i < RC; i += 256) csum[i] = s[i];
}

__global__ __launch_bounds__(256) void scanC(const unsigned int* __restrict__ cnt,
                                             const int* __restrict__ csum,
                                             int* __restrict__ offs,
                                             int* __restrict__ cursor,
                                             int N, int NC) {
    int r = blockIdx.x / NC, c = blockIdx.x % NC;
    int gbase = c * CH;
    const unsigned int* p = cnt + (size_t)r * N + gbase;
    int lim = N - gbase;
    int t = threadIdx.x;
    int i0 = t * 16;
    unsigned int v[16];
    if (i0 + 16 <= lim) {
        const uint4* q = (const uint4*)(p + i0);
        uint4 a0 = q[0], a1 = q[1], a2 = q[2], a3 = q[3];
        v[0]=a0.x; v[1]=a0.y; v[2]=a0.z; v[3]=a0.w;
        v[4]=a1.x; v[5]=a1.y; v[6]=a1.z; v[7]=a1.w;
        v[8]=a2.x; v[9]=a2.y; v[10]=a2.z; v[11]=a2.w;
        v[12]=a3.x; v[13]=a3.y; v[14]=a3.z; v[15]=a3.w;
    } else {
#pragma unroll
        for (int j = 0; j < 16; ++j) v[j] = (i0 + j < lim) ? p[i0 + j] : 0u;
    }
    int tot = 0;
#pragma unroll
    for (int j = 0; j < 16; ++j) tot += (int)v[j];
    int lane = t & 63, w = t >> 6;
    int x = tot;
#pragma unroll
    for (int d = 1; d < 64; d <<= 1) { int y = __shfl_up(x, d, 64); if (lane >= d) x += y; }
    __shared__ int ws[4];
    if (lane == 63) ws[w] = x;
    __syncthreads();
    int wbase = 0;
    for (int k = 0; k < 4; ++k) if (k < w) wbase += ws[k];
    int pre = csum[blockIdx.x] + wbase + (x - tot);
    int* o  = offs   + (size_t)r * N + gbase;
    int* cu = cursor + (size_t)r * N + gbase;
#pragma unroll
    for (int j = 0; j < 16; ++j) {
        int i = i0 + j;
        if (i < lim) { o[i] = pre; cu[i] = pre; }
        pre += (int)v[j];
    }
}

// ---- counting-sort scatter: bucket[r][pos] = src ----
__global__ __launch_bounds__(256) void bucket_kernel(const int* __restrict__ src,
                                                     const int* __restrict__ dst,
                                                     int* __restrict__ cursor,
                                                     int* __restrict__ bucket,
                                                     int RE, int E, int N) {
    int idx = blockIdx.x * 256 + threadIdx.x;
    if (idx >= RE) return;
    int r = idx / E;
    int d = dst[idx];
    int pos = atomicAdd(&cursor[(size_t)r * N + d], 1);
    bucket[(size_t)r * E + pos] = src[idx];
}

// ---- fused 3-relation GEMM: T[r][n][c] = bf16( normO[r][n] * (X @ W_r)[n][c] ) ----
template <bool BF16IN>
__global__ __launch_bounds__(256) void gemm3(const void* __restrict__ Xp,
                                             const unsigned short* __restrict__ WbfT, // [3][128][128] n-major
                                             const float* __restrict__ normO,        // [3][N]
                                             unsigned short* __restrict__ T,         // [3][N][128]
                                             int nrows) {
    __shared__ unsigned short Xl[64 * LDW];
    __shared__ unsigned short Wl[128 * LDW];
    int tid = threadIdx.x;
    int row0 = blockIdx.x * 64;

    // stage X tile as bf16
#pragma unroll
    for (int j = 0; j < 8; ++j) {
        int f4 = tid + j * 256;           // 64 rows * 32 chunks of 4 elems
        int row = f4 >> 5;
        int k0 = (f4 & 31) * 4;
        int gr = row0 + row;
        if (BF16IN) {
            uint2 v = make_uint2(0u, 0u);
            if (gr < nrows) v = ((const uint2*)Xp)[(size_t)gr * 32 + (f4 & 31)];
            *(uint2*)(&Xl[row * LDW + k0]) = v;
        } else {
            float4 v = make_float4(0.f, 0.f, 0.f, 0.f);
            if (gr < nrows) v = ((const float4*)Xp)[(size_t)gr * 32 + (f4 & 31)];
            unsigned long long pk = (unsigned long long)f2bf(v.x)
                                  | ((unsigned long long)f2bf(v.y) << 16)
                                  | ((unsigned long long)f2bf(v.z) << 32)
                                  | ((unsigned long long)f2bf(v.w) << 48);
            *(unsigned long long*)(&Xl[row * LDW + k0]) = pk;
        }
    }
    // stage W[0]: 128*128 shorts = 2048 uint4 chunks -> 8 iterations of 256 threads
#pragma unroll
    for (int j = 0; j < 8; ++j) {
        int i = tid + j * 256;            // 0..2047 chunks of 8 shorts
        int row = i >> 4, c0 = (i & 15) * 8;
        *(uint4*)(Wl + row * LDW + c0) = ((const uint4*)WbfT)[i];
    }
    __syncthreads();

    int wave = tid >> 6, lane = tid & 63;
    int laneM = lane & 15, quad = lane >> 4;
    int m0 = wave * 16;

    // A fragments once (Xl is never overwritten)
    s16x8 afr[4];
#pragma unroll
    for (int ks = 0; ks < 4; ++ks)
        afr[ks] = *(const s16x8*)(Xl + (m0 + laneM) * LDW + ks * 32 + quad * 8);

    for (int r = 0; r < 3; ++r) {
        f32x4 acc[8];
#pragma unroll
        for (int ct = 0; ct < 8; ++ct) acc[ct] = (f32x4){0.f, 0.f, 0.f, 0.f};
#pragma unroll
        for (int ks = 0; ks < 4; ++ks) {
            int k = ks * 32 + quad * 8;
#pragma unroll
            for (int ct = 0; ct < 8; ++ct) {
                s16x8 b = *(const s16x8*)(Wl + (ct * 16 + laneM) * LDW + k);
                acc[ct] = __builtin_amdgcn_mfma_f32_16x16x32_bf16(afr[ks], b, acc[ct], 0, 0, 0);
            }
        }
        // epilogue: D[row=quad*4+i][col=lane&15]
        unsigned short* Tr = T + (size_t)r * nrows * 128;
        const float* nrm = normO + (size_t)r * nrows;
#pragma unroll
        for (int i = 0; i < 4; ++i) {
            int gr = row0 + m0 + quad * 4 + i;
            if (gr < nrows) {
                float sc = nrm[gr];
#pragma unroll
                for (int ct = 0; ct < 8; ++ct)
                    Tr[(size_t)gr * 128 + ct * 16 + laneM] = f2bf(acc[ct][i] * sc);
            }
        }
        if (r < 2) {
            __syncthreads();             // all MFMA reads of Wl done
#pragma unroll
            for (int j = 0; j < 8; ++j) {
                int i = tid + j * 256;
                int row = i >> 4, c0 = (i & 15) * 8;
                *(uint4*)(Wl + row * LDW + c0) =
                    ((const uint4*)(WbfT + (size_t)(r + 1) * 16384))[i];
            }
            __syncthreads();
        }
    }
}

// ---- gather: one wave per dst node, fused over R relations + bias (+relu) ----
template <bool RELU, bool BF16OUT>
__global__ __launch_bounds__(256) void gather_kernel(const unsigned short* __restrict__ T, // [R][N][128]
                                                     const int* __restrict__ bucket,       // [R][E]
                                                     const int* __restrict__ offs,         // [R][N]
                                                     const unsigned int* __restrict__ cnt, // [R][N]
                                                     const float* __restrict__ normI,      // [R][N]
                                                     const float* __restrict__ bias,       // [R][128]
                                                     void* __restrict__ out,
                                                     int N, int E) {
    int n = blockIdx.x * 4 + (threadIdx.x >> 6);
    if (n >= N) return;
    int lane = threadIdx.x & 63;
    float a0 = 0.f, a1 = 0.f;
    const float2* bv = (const float2*)bias;
#pragma unroll
    for (int r = 0; r < 3; ++r) {
        float p0 = 0.f, p1 = 0.f;
        int start = offs[(size_t)r * N + n];
        int c = (int)cnt[(size_t)r * N + n];
        const unsigned int* Tr = (const unsigned int*)(T + (size_t)r * N * 128);
        const int* bk = bucket + (size_t)r * E + start;
        for (int base = 0; base < c; base += 64) {
            int m = min(64, c - base);
            int id = (lane < m) ? bk[base + lane] : 0;
            for (int j = 0; j < m; ++j) {
                int s2 = __shfl(id, j, 64);
                unsigned int v = Tr[(size_t)s2 * 64 + lane];
                p0 += bf2f(v & 0xffffu);
                p1 += bf2f(v >> 16);
            }
        }
        float nd = normI[(size_t)r * N + n];
        float2 bb = bv[r * 64 + lane];
        a0 += p0 * nd + bb.x;
        a1 += p1 * nd + bb.y;
    }
    if (RELU) { a0 = fmaxf(a0, 0.f); a1 = fmaxf(a1, 0.f); }
    if (BF16OUT) {
        unsigned int pk = (unsigned int)f2bf(a0) | ((unsigned int)f2bf(a1) << 16);
        ((unsigned int*)out)[(size_t)n * 64 + lane] = pk;
    } else {
        ((float2*)((float*)out + (size_t)n * 128))[lane] = make_float2(a0, a1);
    }
}

extern "C" void kernel_launch(void* const* d_in, const int* in_sizes, int n_in,
                              void* d_out, int out_size, void* d_ws, size_t ws_size,
                              hipStream_t stream) {
    const float* x  = (const float*)d_in[0];
    const int* src  = (const int*)d_in[1];
    const int* dst  = (const int*)d_in[2];
    const float* W1 = (const float*)d_in[3];
    const float* b1 = (const float*)d_in[4];
    const float* W2 = (const float*)d_in[5];
    const float* b2 = (const float*)d_in[6];
    float* out = (float*)d_out;

    const int R = 3;
    int N = in_sizes[0] / 128;
    int E = in_sizes[1] / R;
    int RN = R * N, RE = R * E;
    int NC = (N + CH - 1) / CH;

    size_t h1b = (size_t)N * 128 * 2;          // bf16 hidden
    size_t Tb  = (size_t)R * N * 128 * 2;      // bf16 messages, all relations
    size_t ib  = (size_t)RN * 4;               // one int/float [R][N] array
    size_t bb  = (size_t)RE * 4;               // bucketed src ids
    size_t wb  = (size_t)2 * R * 16384 * 2;    // bf16 transposed weights
    size_t cb  = (size_t)((R * NC * 4 + 255) & ~255);
    if (ws_size < h1b + Tb + 6 * ib + bb + wb + cb) return;

    char* w = (char*)d_ws;
    unsigned short* h1   = (unsigned short*)w;            w += h1b;
    unsigned short* T    = (unsigned short*)w;            w += Tb;
    unsigned int* cntO   = (unsigned int*)w;              w += ib;
    unsigned int* cntI   = (unsigned int*)w;              w += ib;
    float* normO         = (float*)w;                     w += ib;
    float* normI         = (float*)w;                     w += ib;
    int* offs            = (int*)w;                       w += ib;
    int* cursor          = (int*)w;                       w += ib;
    int* bucket          = (int*)w;                       w += bb;
    unsigned short* WbfT = (unsigned short*)w;            w += wb;
    int* csum            = (int*)w;

    hipMemsetAsync(cntO, 0, 2 * ib, stream);   // cntO + cntI contiguous

    wconv_kernel<<<(2 * R * 16384 + 255) / 256, 256, 0, stream>>>(W1, W2, WbfT, 2 * R * 16384);
    deg_kernel<<<(RE + 255) / 256, 256, 0, stream>>>(src, dst, cntO, cntI, RE, E, N);
    norm_kernel<<<(2 * RN + 255) / 256, 256, 0, stream>>>(cntO, cntI, normO, normI, RN);
    scanA<<<R * NC, 256, 0, stream>>>(cntI, csum, N, NC);
    scanB<<<1, 256, 0, stream>>>(csum, R * NC, NC);
    scanC<<<R * NC, 256, 0, stream>>>(cntI, csum, offs, cursor, N, NC);
    bucket_kernel<<<(RE + 255) / 256, 256, 0, stream>>>(src, dst, cursor, bucket, RE, E, N);

    int gb = (N + 63) / 64;
    int ngb = (N + 3) / 4;

    // layer 1
    gemm3<false><<<gb, 256, 0, stream>>>(x, WbfT, normO, T, N);
    gather_kernel<true, true><<<ngb, 256, 0, stream>>>(T, bucket, offs, cntI, normI, b1, h1, N, E);

    // layer 2
    gemm3<true><<<gb, 256, 0, stream>>>(h1, WbfT + (size_t)3 * 16384, normO, T, N);
    gather_kernel<false, false><<<ngb, 256, 0, stream>>>(T, bucket, offs, cntI, normI, b2, out, N, E);
}